// Round 7
// baseline (5444.189 us; speedup 1.0000x reference)
//
#include <hip/hip_runtime.h>
#include <hip/hip_bf16.h>

typedef __attribute__((ext_vector_type(8))) short bf16x8;
typedef __attribute__((ext_vector_type(4))) float f32x4;
typedef __attribute__((ext_vector_type(4))) unsigned u32x4;

__device__ __forceinline__ ushort f2b(float f) {
    union { float f; unsigned u; } v; v.f = f;
    unsigned r = v.u + 0x7FFFu + ((v.u >> 16) & 1u);
    return (ushort)(r >> 16);
}
__device__ __forceinline__ float b2f(ushort u) {
    union { unsigned u; float f; } v; v.u = ((unsigned)u) << 16;
    return v.f;
}
__device__ __forceinline__ float sigm(float x) {
    return 1.f / (1.f + __expf(-x));
}

// Coherent (device-visible) load/store, literal byte offset.
// NOTE: asm loads are NOT tracked by the compiler's waitcnt insertion —
// every consumer of an HLOAD result must sit behind an explicit
// s_waitcnt vmcnt(N) + sched_barrier(0).
#define HLOAD(dst, p, off) \
    asm volatile("global_load_dwordx4 %0, %1, off offset:" #off " sc0 sc1" \
                 : "=v"(dst) : "v"(p))
#define HSTORE(p, v) \
    asm volatile("global_store_dword %0, %1, off sc0 sc1" \
                 :: "v"(p), "v"(v) : "memory")

// ---------------------------------------------------------------------------
// prep_weights: f32 -> bf16 weight conversion + bias sum (b_ih + b_hh).
// ---------------------------------------------------------------------------
__global__ __launch_bounds__(256) void prep_weights(
    const float* __restrict__ wih0, const float* __restrict__ whh0,
    const float* __restrict__ bih0, const float* __restrict__ bhh0,
    const float* __restrict__ wih1, const float* __restrict__ whh1,
    const float* __restrict__ bih1, const float* __restrict__ bhh1,
    ushort* __restrict__ wih0b, ushort* __restrict__ whh0b,
    ushort* __restrict__ wih1b, ushort* __restrict__ whh1b,
    float* __restrict__ bsum0, float* __restrict__ bsum1)
{
    const int i = blockIdx.x * 256 + threadIdx.x;
    const int e = i * 4;
    float4 v;
    v = *(const float4*)&wih0[e];
    *(ushort4*)&wih0b[e] = make_ushort4(f2b(v.x), f2b(v.y), f2b(v.z), f2b(v.w));
    v = *(const float4*)&whh0[e];
    *(ushort4*)&whh0b[e] = make_ushort4(f2b(v.x), f2b(v.y), f2b(v.z), f2b(v.w));
    v = *(const float4*)&wih1[e];
    *(ushort4*)&wih1b[e] = make_ushort4(f2b(v.x), f2b(v.y), f2b(v.z), f2b(v.w));
    v = *(const float4*)&whh1[e];
    *(ushort4*)&whh1b[e] = make_ushort4(f2b(v.x), f2b(v.y), f2b(v.z), f2b(v.w));
    if (i < 1024) {
        const int b4 = i * 4;
        float4 a0 = *(const float4*)&bih0[b4];
        float4 b0 = *(const float4*)&bhh0[b4];
        *(float4*)&bsum0[b4] = make_float4(a0.x + b0.x, a0.y + b0.y, a0.z + b0.z, a0.w + b0.w);
        float4 a1 = *(const float4*)&bih1[b4];
        float4 b1 = *(const float4*)&bhh1[b4];
        *(float4*)&bsum1[b4] = make_float4(a1.x + b1.x, a1.y + b1.y, a1.z + b1.z, a1.w + b1.w);
    }
}

// ---------------------------------------------------------------------------
// gather_x: xg[row][:] = bf16(emb[idx[row]][:]); row = t*64+b, 16384 rows.
// ---------------------------------------------------------------------------
__global__ __launch_bounds__(256) void gather_x(
    const int* __restrict__ idx, const float* __restrict__ emb,
    ushort* __restrict__ xg)
{
    const int row = blockIdx.x;
    const int c = threadIdx.x;
    const int v = idx[row];
    const float4 f = *(const float4*)&emb[(size_t)v * 1024u + c * 4];
    *(ushort4*)&xg[(size_t)row * 1024u + c * 4] =
        make_ushort4(f2b(f.x), f2b(f.y), f2b(f.z), f2b(f.w));
}

// ---------------------------------------------------------------------------
// inproj_mfma: xp[m][g] = sum_k A[mbase+m][k]*W[g][k] + bsum[g]  (bf16 out)
// 128x128 tile, 4 waves x 64x64, 16x16x32 bf16 MFMA.
// ---------------------------------------------------------------------------
__global__ __launch_bounds__(256) void inproj_mfma(
    const ushort* __restrict__ A, const ushort* __restrict__ W,
    const float* __restrict__ bsum, ushort* __restrict__ xpout, int mbase)
{
    __shared__ ushort As[128][72];
    __shared__ ushort Bsh[128][72];
    const int tid = threadIdx.x;
    const int wv = tid >> 6, lane = tid & 63;
    const int l15 = lane & 15, l4 = lane >> 4;
    const int m0 = blockIdx.y * 128, n0 = blockIdx.x * 128;
    const int wm = (wv & 1) * 64, wn = (wv >> 1) * 64;

    f32x4 acc[4][4];
    #pragma unroll
    for (int i = 0; i < 4; ++i)
        #pragma unroll
        for (int j = 0; j < 4; ++j) acc[i][j] = (f32x4){0.f, 0.f, 0.f, 0.f};

    for (int k0 = 0; k0 < 1024; k0 += 64) {
        __syncthreads();
        #pragma unroll
        for (int s4 = 0; s4 < 4; ++s4) {
            const int s = tid + s4 * 256;
            const int row = s >> 3, c8 = (s & 7) * 8;
            *(bf16x8*)&As[row][c8] =
                *(const bf16x8*)&A[(size_t)(mbase + m0 + row) * 1024u + k0 + c8];
            *(bf16x8*)&Bsh[row][c8] =
                *(const bf16x8*)&W[(size_t)(n0 + row) * 1024u + k0 + c8];
        }
        __syncthreads();
        #pragma unroll
        for (int kk = 0; kk < 2; ++kk) {
            bf16x8 af[4], bfr[4];
            #pragma unroll
            for (int i = 0; i < 4; ++i) {
                af[i]  = *(const bf16x8*)&As[wm + i * 16 + l15][kk * 32 + l4 * 8];
                bfr[i] = *(const bf16x8*)&Bsh[wn + i * 16 + l15][kk * 32 + l4 * 8];
            }
            #pragma unroll
            for (int i = 0; i < 4; ++i)
                #pragma unroll
                for (int j = 0; j < 4; ++j)
                    acc[i][j] = __builtin_amdgcn_mfma_f32_16x16x32_bf16(
                        af[i], bfr[j], acc[i][j], 0, 0, 0);
        }
    }
    #pragma unroll
    for (int i = 0; i < 4; ++i) {
        const int m = m0 + wm + i * 16 + l4 * 4;
        #pragma unroll
        for (int j = 0; j < 4; ++j) {
            const int g = n0 + wn + j * 16 + l15;
            const float bs = bsum[g];
            #pragma unroll
            for (int r = 0; r < 4; ++r)
                xpout[(size_t)(m + r) * 4096u + g] = f2b(acc[i][j][r] + bs);
        }
    }
}

// ---------------------------------------------------------------------------
// lstm_persist: 64 timesteps, 128 blocks x 256 thr (4 fully-independent waves).
// Block owns hc slice [bid*8, bid*8+8): 32 gate rows in LDS. Wave wv owns
// batch rows [wv*16, wv*16+16) over the FULL K=1024 (M=16, N=32, 64 MFMA).
// No cross-wave reduce, NO __syncthreads in the step loop. Per-wave flags
// (512): flag[bid*4+wv] = global step id done. A wave polls all 512 flags
// (8/lane, explicit waitcnt before consuming!), loads h coherently (counted
// vmcnt overlap with MFMA), computes gates, pointwise, stores h, acks,
// signals its flag.
// ---------------------------------------------------------------------------
__global__ __launch_bounds__(256, 1) void lstm_persist(
    const ushort* __restrict__ Whh,   // bf16 [4096][1024]
    const ushort* __restrict__ xp,    // bf16 [4096 m][4096 g] chunk rows
    ushort* __restrict__ hbuf,        // bf16 [2][64][1024] ping-pong
    float* __restrict__ cbuf,         // f32 [64][1024]
    ushort* __restrict__ ys,          // bf16 [16384][1024] or null
    float* __restrict__ outHC,        // h0,h1,c0,c1 each 64x1024 f32
    unsigned* __restrict__ flags,     // [512] monotonic per-wave step flags
    int t0, int nt, int layer)
{
    __shared__ ushort Ws[32][1032];   // 66 KB, row = hcl*4+q
    __shared__ float gs[4][16][33];   // 8.4 KB per-wave gate sums

    const int tid = threadIdx.x;
    const int wv = tid >> 6, lane = tid & 63;
    const int l15 = lane & 15, l4 = lane >> 4;
    const int bid = blockIdx.x;
    const int hc0 = bid * 8;

    // stage weights: LDS row = hcl*4+q  <->  g = q*1024 + hc0 + hcl
    for (int s = tid; s < 32 * 128; s += 256) {
        const int row = s >> 7, c8 = (s & 127) * 8;
        const int g = (row & 3) * 1024 + hc0 + (row >> 2);
        *(bf16x8*)&Ws[row][c8] = *(const bf16x8*)&Whh[(size_t)g * 1024u + c8];
    }

    // pointwise ownership: pb = wv*16 + (lane>>2), hc pair pp = lane&3
    const int pb = wv * 16 + (lane >> 2);
    const int pp = lane & 3;
    float cs[2];
    if (t0 == 0) { cs[0] = cs[1] = 0.f; }
    else {
        float2 c2 = *(const float2*)&cbuf[(size_t)pb * 1024u + hc0 + 2 * pp];
        cs[0] = c2.x; cs[1] = c2.y;
    }
    __syncthreads();   // Ws ready (once per dispatch)

    const unsigned* xpu = (const unsigned*)xp;
    const u32x4* f4 = (const u32x4*)flags;
    const int myflag = bid * 4 + wv;

    for (int ts = 0; ts < nt; ++ts) {
        const int t = t0 + ts;
        const unsigned need = (unsigned)(layer * 256 + t);
        const ushort* hr = hbuf + (size_t)(t & 1) * 65536u;

        // xp prefetch (cached; completes under the poll)
        unsigned xq[4];
        #pragma unroll
        for (int q = 0; q < 4; ++q)
            xq[q] = xpu[(size_t)(ts * 64 + pb) * 2048u + q * 512 + (hc0 >> 1) + pp];

        // poll ALL 512 per-wave flags: 8 per lane via two coherent dwordx4.
        // MUST waitcnt before consuming asm-load results (compiler won't).
        for (;;) {
            u32x4 fa, fb;
            HLOAD(fa, f4 + lane, 0);
            HLOAD(fb, f4 + lane, 1024);
            asm volatile("s_waitcnt vmcnt(0)" ::: "memory");
            __builtin_amdgcn_sched_barrier(0);
            unsigned mna = min(min(fa[0], fa[1]), min(fa[2], fa[3]));
            unsigned mnb = min(min(fb[0], fb[1]), min(fb[2], fb[3]));
            if (__all(min(mna, mnb) >= need)) break;
            __builtin_amdgcn_s_sleep(1);
        }
        // vmcnt already 0 here (poll drained); counted waits below are exact.

        // h loads: 16 rows (wv*16+l15) x K=1024, 32 x dwordx4, imm offsets
        bf16x8 hf[32];
        const ushort* rbase = hr + (size_t)(wv * 16 + l15) * 1024u + l4 * 8;
        HLOAD(hf[0],  rbase, 0);    HLOAD(hf[1],  rbase, 64);
        HLOAD(hf[2],  rbase, 128);  HLOAD(hf[3],  rbase, 192);
        HLOAD(hf[4],  rbase, 256);  HLOAD(hf[5],  rbase, 320);
        HLOAD(hf[6],  rbase, 384);  HLOAD(hf[7],  rbase, 448);
        HLOAD(hf[8],  rbase, 512);  HLOAD(hf[9],  rbase, 576);
        HLOAD(hf[10], rbase, 640);  HLOAD(hf[11], rbase, 704);
        HLOAD(hf[12], rbase, 768);  HLOAD(hf[13], rbase, 832);
        HLOAD(hf[14], rbase, 896);  HLOAD(hf[15], rbase, 960);
        HLOAD(hf[16], rbase, 1024); HLOAD(hf[17], rbase, 1088);
        HLOAD(hf[18], rbase, 1152); HLOAD(hf[19], rbase, 1216);
        HLOAD(hf[20], rbase, 1280); HLOAD(hf[21], rbase, 1344);
        HLOAD(hf[22], rbase, 1408); HLOAD(hf[23], rbase, 1472);
        HLOAD(hf[24], rbase, 1536); HLOAD(hf[25], rbase, 1600);
        HLOAD(hf[26], rbase, 1664); HLOAD(hf[27], rbase, 1728);
        HLOAD(hf[28], rbase, 1792); HLOAD(hf[29], rbase, 1856);
        HLOAD(hf[30], rbase, 1920); HLOAD(hf[31], rbase, 1984);

        f32x4 acc0 = (f32x4){0.f, 0.f, 0.f, 0.f};
        f32x4 acc1 = (f32x4){0.f, 0.f, 0.f, 0.f};

#define MFMA_GRP(G) \
        _Pragma("unroll") \
        for (int kk2 = 0; kk2 < 8; ++kk2) { \
            const int kk = (G) * 8 + kk2; \
            const int k = kk * 32 + l4 * 8; \
            bf16x8 b0 = *(const bf16x8*)&Ws[l15][k]; \
            bf16x8 b1 = *(const bf16x8*)&Ws[16 + l15][k]; \
            acc0 = __builtin_amdgcn_mfma_f32_16x16x32_bf16(hf[kk], b0, acc0, 0, 0, 0); \
            acc1 = __builtin_amdgcn_mfma_f32_16x16x32_bf16(hf[kk], b1, acc1, 0, 0, 0); \
        }

        asm volatile("s_waitcnt vmcnt(24)" ::: "memory");
        __builtin_amdgcn_sched_barrier(0);
        MFMA_GRP(0)
        asm volatile("s_waitcnt vmcnt(16)" ::: "memory");
        __builtin_amdgcn_sched_barrier(0);
        MFMA_GRP(1)
        asm volatile("s_waitcnt vmcnt(8)" ::: "memory");
        __builtin_amdgcn_sched_barrier(0);
        MFMA_GRP(2)
        asm volatile("s_waitcnt vmcnt(0)" ::: "memory");
        __builtin_amdgcn_sched_barrier(0);
        MFMA_GRP(3)
#undef MFMA_GRP

        // wave-local gate-sum bounce: gs[wv][m_row][n]; n = hcl*4+q
        #pragma unroll
        for (int r = 0; r < 4; ++r) {
            gs[wv][l4 * 4 + r][l15]      = acc0[r];
            gs[wv][l4 * 4 + r][16 + l15] = acc1[r];
        }

        // pointwise: lane owns (pb, hc = hc0 + 2*pp + {0,1})
        ushort* hw = hbuf + (size_t)((t + 1) & 1) * 65536u;
        float hv[2];
        #pragma unroll
        for (int d = 0; d < 2; ++d) {
            const int grow = (2 * pp + d) * 4;
            const float g0 = gs[wv][lane >> 2][grow + 0] + b2f((ushort)(d ? (xq[0] >> 16) : (xq[0] & 0xffff)));
            const float g1 = gs[wv][lane >> 2][grow + 1] + b2f((ushort)(d ? (xq[1] >> 16) : (xq[1] & 0xffff)));
            const float g2 = gs[wv][lane >> 2][grow + 2] + b2f((ushort)(d ? (xq[2] >> 16) : (xq[2] & 0xffff)));
            const float g3 = gs[wv][lane >> 2][grow + 3] + b2f((ushort)(d ? (xq[3] >> 16) : (xq[3] & 0xffff)));
            const float ig = sigm(g0), fg = sigm(g1);
            const float gg = tanhf(g2), og = sigm(g3);
            const float c = fg * cs[d] + ig * gg;
            hv[d] = og * tanhf(c);
            cs[d] = c;
        }
        const unsigned hpack = (unsigned)f2b(hv[0]) | ((unsigned)f2b(hv[1]) << 16);
        unsigned* hwp = (unsigned*)(hw + (size_t)pb * 1024u + hc0 + 2 * pp);
        HSTORE(hwp, hpack);
        asm volatile("s_waitcnt vmcnt(0)" ::: "memory");   // store acked

        if (lane == 0) {
            unsigned* fp = &flags[myflag];
            HSTORE(fp, need + 1);
        }

        // deferred cached stores (consumed only by later dispatches)
        if (ys)
            *(unsigned*)(ys + (size_t)(t * 64 + pb) * 1024u + hc0 + 2 * pp) = hpack;
        if (t == 255) {
            #pragma unroll
            for (int d = 0; d < 2; ++d) {
                const int hc = hc0 + 2 * pp + d;
                outHC[(size_t)layer * 65536u + (size_t)pb * 1024u + hc] = hv[d];
                outHC[131072u + (size_t)layer * 65536u + (size_t)pb * 1024u + hc] = cs[d];
            }
        }
    }

    *(float2*)&cbuf[(size_t)pb * 1024u + hc0 + 2 * pp] = make_float2(cs[0], cs[1]);
}

// ---------------------------------------------------------------------------
extern "C" void kernel_launch(void* const* d_in, const int* in_sizes, int n_in,
                              void* d_out, int out_size, void* d_ws, size_t ws_size,
                              hipStream_t stream) {
    (void)in_sizes; (void)n_in; (void)out_size; (void)ws_size;
    const int*   idx  = (const int*)d_in[0];
    const float* emb  = (const float*)d_in[1];
    const float* wih[2] = {(const float*)d_in[2], (const float*)d_in[6]};
    const float* whh[2] = {(const float*)d_in[3], (const float*)d_in[7]};
    const float* bih[2] = {(const float*)d_in[4], (const float*)d_in[8]};
    const float* bhh[2] = {(const float*)d_in[5], (const float*)d_in[9]};
    float* out = (float*)d_out;

    char* p = (char*)d_ws;
    ushort* xg    = (ushort*)p;  p += 33554432;   // 16384x1024 bf16
    ushort* ys0   = (ushort*)p;  p += 33554432;   // 16384x1024 bf16
    ushort* wihb0 = (ushort*)p;  p += 8388608;
    ushort* whhb0 = (ushort*)p;  p += 8388608;
    ushort* wihb1 = (ushort*)p;  p += 8388608;
    ushort* whhb1 = (ushort*)p;  p += 8388608;
    ushort* xp    = (ushort*)p;  p += 33554432;   // [4096 m][4096 g] bf16 chunk
    ushort* hbuf  = (ushort*)p;  p += 262144;     // 2x64x1024 bf16
    float*  cbuf  = (float*)p;   p += 262144;     // 64x1024 f32
    float*  bsum0 = (float*)p;   p += 16384;
    float*  bsum1 = (float*)p;   p += 16384;
    unsigned* flags = (unsigned*)p;               // 512 x u32 per-wave flags

    hipMemsetAsync(flags, 0, 2048, stream);
    prep_weights<<<4096, 256, 0, stream>>>(
        wih[0], whh[0], bih[0], bhh[0], wih[1], whh[1], bih[1], bhh[1],
        wihb0, whhb0, wihb1, whhb1, bsum0, bsum1);
    gather_x<<<16384, 256, 0, stream>>>(idx, emb, xg);

    const ushort* wihbL[2] = {wihb0, wihb1};
    const ushort* whhbL[2] = {whhb0, whhb1};
    const float*  bsumL[2] = {bsum0, bsum1};

    for (int L = 0; L < 2; ++L) {
        hipMemsetAsync(hbuf, 0, 262144, stream);
        const ushort* Abase = (L == 0) ? xg : ys0;
        ushort* ysout = (L == 0) ? ys0 : nullptr;
        for (int ch = 0; ch < 4; ++ch) {
            inproj_mfma<<<dim3(32, 32), 256, 0, stream>>>(
                Abase, wihbL[L], bsumL[L], xp, ch * 4096);
            lstm_persist<<<128, 256, 0, stream>>>(
                whhbL[L], xp, hbuf, cbuf, ysout, out, flags, ch * 64, 64, L);
        }
    }
}